// Round 13
// baseline (444.039 us; speedup 1.0000x reference)
//
#include <hip/hip_runtime.h>
#include <cstddef>

#define NSTATES 32
#define SEQLEN 4096
#define NBATCH 256
#define CHUNK 8
#define HALO 32
#define NCHUNKS 512                 // SEQLEN / CHUNK
#define SPAN_MAX 40                 // CHUNK + HALO

#define F_LOG2E 1.44269504088896340736f
#define F_LN2   0.69314718055994530942f
#define F_NEG_HALF_LOG2PI -0.91893853320467274178f
#define SCALE60 1.152921504606847e18f   // 2^60 on stored phi
#define SCALE30 1.073741824e9f          // 2^30 on stored b

#define EXP2F(x) __builtin_amdgcn_exp2f(x)
#define LOG2F(x) __builtin_amdgcn_logf(x)   // v_log_f32 == log2, despite the name
#define RCPF(x)  __builtin_amdgcn_rcpf(x)

typedef __attribute__((ext_vector_type(8)))  short short8;
typedef __attribute__((ext_vector_type(16))) float f32x16;
typedef __attribute__((ext_vector_type(8)))  unsigned int uintv8;

static __device__ __forceinline__ unsigned int pkbf(float lo, float hi) {
    unsigned int r;
    asm("v_cvt_pk_bf16_f32 %0, %1, %2" : "=v"(r) : "v"(lo), "v"(hi));
    return r;
}
static __device__ __forceinline__ void swp32(unsigned int& a, unsigned int& b) {
    asm volatile("v_permlane32_swap_b32 %0, %1" : "+v"(a), "+v"(b));
}
static __device__ __forceinline__ float xhalf_max(float v) {
    float a = v, b;
    asm("v_mov_b32 %0, %1" : "=v"(b) : "v"(v));
    asm volatile("v_permlane32_swap_b32 %0, %1" : "+v"(a), "+v"(b));
    return fmaxf(a, b);
}
static __device__ __forceinline__ float xhalf_add(float v) {
    float a = v, b;
    asm("v_mov_b32 %0, %1" : "=v"(b) : "v"(v));
    asm volatile("v_permlane32_swap_b32 %0, %1" : "+v"(a), "+v"(b));
    return a + b;
}
static __device__ __forceinline__ float vtmax(const f32x16& d) {
    return fmaxf(
      fmaxf(fmaxf(fmaxf(d[0],d[1]),fmaxf(d[2],d[3])), fmaxf(fmaxf(d[4],d[5]),fmaxf(d[6],d[7]))),
      fmaxf(fmaxf(fmaxf(d[8],d[9]),fmaxf(d[10],d[11])), fmaxf(fmaxf(d[12],d[13]),fmaxf(d[14],d[15]))));
}
static __device__ __forceinline__ float vtsum(const f32x16& d) {
    return ((((d[0]+d[1])+(d[2]+d[3])) + ((d[4]+d[5])+(d[6]+d[7])))
          + (((d[8]+d[9])+(d[10]+d[11])) + ((d[12]+d[13])+(d[14]+d[15]))));
}
// B-frags use the SAME (h,e)->k map as the A-frags, so k-permutation cancels.
static __device__ __forceinline__ void make_frags(const f32x16& q, short8& lo, short8& hi) {
    unsigned int X  = pkbf(q[0],  q[1]),  Z  = pkbf(q[2],  q[3]);
    unsigned int Y  = pkbf(q[4],  q[5]),  W  = pkbf(q[6],  q[7]);
    unsigned int X2 = pkbf(q[8],  q[9]),  Z2 = pkbf(q[10], q[11]);
    unsigned int Y2 = pkbf(q[12], q[13]), W2 = pkbf(q[14], q[15]);
    swp32(X, Y); swp32(Z, W); swp32(X2, Y2); swp32(Z2, W2);
    union { unsigned int w[4]; short8 s; } u;
    u.w[0] = X;  u.w[1] = Z;  u.w[2] = Y;  u.w[3] = W;  lo = u.s;
    u.w[0] = X2; u.w[1] = Z2; u.w[2] = Y2; u.w[3] = W2; hi = u.s;
}

// bf16 dump slot (offset in ushort units; <<4 = 16 bf16 per lane per t)
#define DUMP_OFF(rg_, t_) ((((size_t)(rg_) * SEQLEN + (t_)) * 64 + lane) << 4)

#define MF_CONSTS_ALL                                                     \
    f32x16 muv, c0v, c1v, li2m;                                           \
    _Pragma("unroll")                                                     \
    for (int i = 0; i < 16; ++i) {                                        \
        int m = (i & 3) + ((i >> 2) << 3) + (h << 2);                     \
        float ls = log_sig[m];                                            \
        muv[i]  = means[m];                                               \
        c1v[i]  = -0.5f * expf(-2.0f * ls) * F_LOG2E;                     \
        c0v[i]  = (-ls + F_NEG_HALF_LOG2PI) * F_LOG2E;                    \
        li2m[i] = log_init[m] * F_LOG2E;                                  \
    }

#define MF_CONSTS_EMIT                                                    \
    f32x16 muv, c0v, c1v;                                                 \
    _Pragma("unroll")                                                     \
    for (int i = 0; i < 16; ++i) {                                        \
        int m = (i & 3) + ((i >> 2) << 3) + (h << 2);                     \
        float ls = log_sig[m];                                            \
        muv[i]  = means[m];                                               \
        c1v[i]  = -0.5f * expf(-2.0f * ls) * F_LOG2E;                     \
        c0v[i]  = (-ls + F_NEG_HALF_LOG2PI) * F_LOG2E;                    \
    }

#define MF_AFRAGS                                                         \
    const float* Ar = Amat + r * 32 + (h << 3);                           \
    float4 a0_ = *(const float4*)(Ar),      a1_ = *(const float4*)(Ar + 4);  \
    float4 a2_ = *(const float4*)(Ar + 16), a3_ = *(const float4*)(Ar + 20); \
    short8 alo, ahi;                                                      \
    {                                                                     \
        union { unsigned int ww[4]; short8 s; } ua;                       \
        ua.ww[0] = pkbf(a0_.x, a0_.y); ua.ww[1] = pkbf(a0_.z, a0_.w);     \
        ua.ww[2] = pkbf(a1_.x, a1_.y); ua.ww[3] = pkbf(a1_.z, a1_.w);     \
        alo = ua.s;                                                       \
        ua.ww[0] = pkbf(a2_.x, a2_.y); ua.ww[1] = pkbf(a2_.z, a2_.w);     \
        ua.ww[2] = pkbf(a3_.x, a3_.y); ua.ww[3] = pkbf(a3_.z, a3_.w);     \
        ahi = ua.s;                                                       \
    }

// stage obvs[row0+rr][tbase .. tbase+span) into xsw[t][rr]; tbase%4==0, span%4==0
#define MF_STAGE(xsw, tbase, span)                                        \
    {                                                                     \
        const float* xr_ = obvs + (size_t)(row0 + r) * SEQLEN + (tbase);  \
        for (int tt = 4 * h; tt + 4 <= (span); tt += 8) {                 \
            float4 v_ = *(const float4*)(xr_ + tt);                       \
            xsw[tt + 0][r] = v_.x; xsw[tt + 1][r] = v_.y;                 \
            xsw[tt + 2][r] = v_.z; xsw[tt + 3][r] = v_.w;                 \
        }                                                                 \
        __threadfence_block();                                            \
    }

// K1: fused fwd+bwd recursions; CHUNK=8, HALO=32, 8192 waves (8/SIMD).
// Renorm = r11-proven full max tree. fwd stores phi_t = d*rs (pre-emission,
// *2^60) bf16; bwd stores b_t = d*rs (*2^30) bf16. Combine adds emission.
__global__ __launch_bounds__(128, 8) void hmm_recurse7(
    const float* __restrict__ obvs, const float* __restrict__ log_init,
    const float* __restrict__ Amat, const float* __restrict__ means,
    const float* __restrict__ log_sig, unsigned short* __restrict__ lfB,
    unsigned short* __restrict__ lbB)
{
    __shared__ float xs[2][SPAN_MAX][32];
    const int tid = threadIdx.x;
    const int w = tid >> 6, lane = tid & 63, h = lane >> 5, r = lane & 31;
    const int wgid2 = blockIdx.x * 2 + w;
    const bool isfwd = (wgid2 < 4096);
    const int wgid = wgid2 & 4095;
    const int chunk = wgid & (NCHUNKS - 1);
    const int rg = wgid >> 9;
    const int row0 = rg << 5;

    MF_CONSTS_ALL;
    MF_AFRAGS;
    const f32x16 zro = (f32x16)0.0f;
    float (*xsw)[32] = xs[w];

    if (isfwd) {
        const int t0 = chunk * CHUNK, t1 = t0 + CHUNK;
        const int ts = (t0 > HALO) ? (t0 - HALO) : 0;
        MF_STAGE(xsw, ts, t1 - ts);
        f32x16 qh;
        {
            float x0 = xsw[0][r];
#pragma unroll
            for (int i = 0; i < 16; ++i) {
                float dx = x0 - muv[i];
                float cur = fmaf(c1v[i] * dx, dx, c0v[i]) + (ts == 0 ? li2m[i] : 0.0f);
                qh[i] = EXP2F(cur);
            }
            if (chunk == 0) {
                // phi_0 = normalized pi (f_0 = phi_0 * ev_0)
                f32x16 u;
#pragma unroll
                for (int i = 0; i < 16; ++i) u[i] = EXP2F(li2m[i]);
                float s = RCPF(xhalf_max(vtmax(u))) * SCALE60;
                uintv8 pk;
#pragma unroll
                for (int k = 0; k < 8; ++k) pk[k] = pkbf(u[2*k] * s, u[2*k+1] * s);
                *(uintv8*)(lfB + DUMP_OFF(rg, 0)) = pk;
            }
        }
        for (int t = ts + 1; t < t1; ++t) {
            short8 blo, bhi; make_frags(qh, blo, bhi);
            f32x16 d = __builtin_amdgcn_mfma_f32_32x32x16_bf16(alo, blo, zro, 0, 0, 0);
            d = __builtin_amdgcn_mfma_f32_32x32x16_bf16(ahi, bhi, d, 0, 0, 0);
            float rs = RCPF(xhalf_max(vtmax(d)));    // r11-proven max tree
            float x = xsw[t - ts][r];
            f32x16 phi;
#pragma unroll
            for (int i = 0; i < 16; ++i) {
                float dx = x - muv[i];
                float e2 = fmaf(c1v[i] * dx, dx, c0v[i]);
                phi[i] = d[i] * rs;
                qh[i] = phi[i] * EXP2F(e2);
            }
            if (t >= t0) {
                uintv8 pk;
#pragma unroll
                for (int k = 0; k < 8; ++k)
                    pk[k] = pkbf(phi[2*k] * SCALE60, phi[2*k+1] * SCALE60);
                *(uintv8*)(lfB + DUMP_OFF(rg, t)) = pk;
            }
        }
    } else {
        const int t0 = chunk * CHUNK, t1 = t0 + CHUNK;
        int tsb = t1 - 1 + HALO;
        if (tsb > SEQLEN - 1) tsb = SEQLEN - 1;
        MF_STAGE(xsw, t0, tsb - t0 + 1);
        f32x16 bh;
        if (tsb == SEQLEN - 1) {
            // exact init b(T-1) = exp2(li2m), max-normalized
            float lm = xhalf_max(vtmax(li2m));
#pragma unroll
            for (int i = 0; i < 16; ++i) bh[i] = EXP2F(li2m[i] - lm);
            if (chunk == NCHUNKS - 1) {
                uintv8 pk;
#pragma unroll
                for (int k = 0; k < 8; ++k)
                    pk[k] = pkbf(bh[2*k] * SCALE30, bh[2*k+1] * SCALE30);
                *(uintv8*)(lbB + DUMP_OFF(rg, SEQLEN - 1)) = pk;
            }
        } else {
#pragma unroll
            for (int i = 0; i < 16; ++i) bh[i] = 1.0f;
        }
        for (int t = tsb - 1; t >= t0; --t) {
            float x = xsw[t + 1 - t0][r];
            f32x16 wv;
#pragma unroll
            for (int i = 0; i < 16; ++i) {
                float dx = x - muv[i];
                float e2 = fmaf(c1v[i] * dx, dx, c0v[i]);
                wv[i] = bh[i] * EXP2F(e2);
            }
            short8 blo, bhi; make_frags(wv, blo, bhi);
            f32x16 d = __builtin_amdgcn_mfma_f32_32x32x16_bf16(alo, blo, zro, 0, 0, 0);
            d = __builtin_amdgcn_mfma_f32_32x32x16_bf16(ahi, bhi, d, 0, 0, 0);
            float rs = RCPF(xhalf_max(vtmax(d)));    // r11-proven max tree
#pragma unroll
            for (int i = 0; i < 16; ++i) bh[i] = d[i] * rs;
            if (t < t1) {
                uintv8 pk;
#pragma unroll
                for (int k = 0; k < 8; ++k)
                    pk[k] = pkbf(bh[2*k] * SCALE30, bh[2*k+1] * SCALE30);
                *(uintv8*)(lbB + DUMP_OFF(rg, t)) = pk;
            }
        }
    }
}

// K2: p = phi * b * ev (ev recomputed from LDS-staged obvs), z = log2(sum),
// out = (log2 p - z)*ln2; transpose via os tile, coalesced f32 writes.
__global__ __launch_bounds__(128) void hmm_combine5(
    const unsigned short* __restrict__ lfB, const unsigned short* __restrict__ lbB,
    const float* __restrict__ obvs, const float* __restrict__ means,
    const float* __restrict__ log_sig, float* __restrict__ out)
{
    __shared__ float os[2][32][128];
    __shared__ float xs2[2][8][32];
    const int tid = threadIdx.x;
    const int w = tid >> 6, lane = tid & 63, h = lane >> 5, r = lane & 31;
    const int wgid2 = blockIdx.x * 2 + w;          // [0,4096)
    const int rg = wgid2 >> 9, c8 = wgid2 & 511;
    const int row0 = rg << 5, tA = c8 << 3;
    const int xr4 = (r & 7) << 2;
    MF_CONSTS_EMIT;

    // stage this wave's 8 t's x 32 rows of obvs: one float4 per lane
    {
        float4 xv = *(const float4*)(obvs + (size_t)(row0 + r) * SEQLEN + tA + 4 * h);
        xs2[w][4*h + 0][r] = xv.x; xs2[w][4*h + 1][r] = xv.y;
        xs2[w][4*h + 2][r] = xv.z; xs2[w][4*h + 3][r] = xv.w;
        __threadfence_block();
    }

    for (int tt = 0; tt < 8; ++tt) {
        int t = tA + tt;
        uintv8 Fw = *(const uintv8*)(lfB + DUMP_OFF(rg, t));
        uintv8 Bw = *(const uintv8*)(lbB + DUMP_OFF(rg, t));
        float x = xs2[w][tt][r];
        f32x16 p;
#pragma unroll
        for (int i = 0; i < 16; ++i) {
            unsigned int fw = Fw[i >> 1], bw = Bw[i >> 1];
            float fv = __int_as_float((i & 1) ? (fw & 0xffff0000u) : (fw << 16));
            float bv = __int_as_float((i & 1) ? (bw & 0xffff0000u) : (bw << 16));
            float dx = x - muv[i];
            float ev = EXP2F(fmaf(c1v[i] * dx, dx, c0v[i]));
            p[i] = fv * bv * ev;
        }
        float z = LOG2F(xhalf_add(vtsum(p)));
        f32x16 g;
#pragma unroll
        for (int i = 0; i < 16; ++i) g[i] = (LOG2F(p[i]) - z) * F_LN2;
        float* orow = &os[w][r][0];
        int cb = ((t & 3) << 5) + (h << 2);
        float4 v0 = {g[0],  g[1],  g[2],  g[3]};
        float4 v1 = {g[4],  g[5],  g[6],  g[7]};
        float4 v2 = {g[8],  g[9],  g[10], g[11]};
        float4 v3 = {g[12], g[13], g[14], g[15]};
        *(float4*)(orow + ((cb + 0)  ^ xr4)) = v0;
        *(float4*)(orow + ((cb + 8)  ^ xr4)) = v1;
        *(float4*)(orow + ((cb + 16) ^ xr4)) = v2;
        *(float4*)(orow + ((cb + 24) ^ xr4)) = v3;
        if ((t & 3) == 3) {
            __threadfence_block();
            int q_ = lane & 3, r2 = lane >> 2;
#pragma unroll
            for (int p_ = 0; p_ < 2; ++p_) {
                int rf = p_ * 16 + r2;
                const float* orf = &os[w][rf][0];
                float* gb = out + (size_t)(row0 + rf) * (SEQLEN * NSTATES)
                                + (size_t)(t - 3) * NSTATES;
#pragma unroll
                for (int k_ = 0; k_ < 8; ++k_) {
                    int L = (k_ << 4) + (q_ << 2);
                    *(float4*)(gb + L) = *(const float4*)(orf + (L ^ ((rf & 7) << 2)));
                }
            }
            __threadfence_block();
        }
    }
}

extern "C" void kernel_launch(void* const* d_in, const int* in_sizes, int n_in,
                              void* d_out, int out_size, void* d_ws, size_t ws_size,
                              hipStream_t stream) {
    const float* obvs     = (const float*)d_in[0];
    const float* log_init = (const float*)d_in[1];
    const float* Amat     = (const float*)d_in[2];
    const float* means    = (const float*)d_in[3];
    const float* log_sig  = (const float*)d_in[4];
    float* out = (float*)d_out;

    const size_t NE = (size_t)NBATCH * SEQLEN * NSTATES;   // 33.5M
    unsigned short* lfB = (unsigned short*)d_ws;           // 67 MB
    unsigned short* lbB = lfB + NE;                        // 67 MB

    hipLaunchKernelGGL(hmm_recurse7, dim3(4096), dim3(128), 0, stream,
                       obvs, log_init, Amat, means, log_sig, lfB, lbB);
    hipLaunchKernelGGL(hmm_combine5, dim3(2048), dim3(128), 0, stream,
                       lfB, lbB, obvs, means, log_sig, out);
}

// Round 14
// 123.178 us; speedup vs baseline: 3.6049x; 3.6049x over previous
//
#include <hip/hip_runtime.h>
#include <cstddef>

#define NSTATES 32
#define SEQLEN 4096
#define NBATCH 256
#define CHUNK 8
#define HALO 32
#define NCHUNKS 512                 // SEQLEN / CHUNK
#define SPAN_MAX 40                 // CHUNK + HALO

#define F_LOG2E 1.44269504088896340736f
#define F_LN2   0.69314718055994530942f
#define F_NEG_HALF_LOG2PI -0.91893853320467274178f
#define SCALE60 1.152921504606847e18f   // 2^60 on stored phi (cancels in softmax z)

#define EXP2F(x) __builtin_amdgcn_exp2f(x)
#define LOG2F(x) __builtin_amdgcn_logf(x)   // v_log_f32 == log2, despite the name
#define RCPF(x)  __builtin_amdgcn_rcpf(x)

typedef __attribute__((ext_vector_type(8)))  short short8;
typedef __attribute__((ext_vector_type(16))) float f32x16;
typedef __attribute__((ext_vector_type(8)))  unsigned int uintv8;

static __device__ __forceinline__ unsigned int pkbf(float lo, float hi) {
    unsigned int r;
    asm("v_cvt_pk_bf16_f32 %0, %1, %2" : "=v"(r) : "v"(lo), "v"(hi));
    return r;
}
static __device__ __forceinline__ void swp32(unsigned int& a, unsigned int& b) {
    asm volatile("v_permlane32_swap_b32 %0, %1" : "+v"(a), "+v"(b));
}
static __device__ __forceinline__ float xhalf_max(float v) {
    float a = v, b;
    asm("v_mov_b32 %0, %1" : "=v"(b) : "v"(v));
    asm volatile("v_permlane32_swap_b32 %0, %1" : "+v"(a), "+v"(b));
    return fmaxf(a, b);
}
static __device__ __forceinline__ float xhalf_add(float v) {
    float a = v, b;
    asm("v_mov_b32 %0, %1" : "=v"(b) : "v"(v));
    asm volatile("v_permlane32_swap_b32 %0, %1" : "+v"(a), "+v"(b));
    return a + b;
}
static __device__ __forceinline__ float vtmax(const f32x16& d) {
    return fmaxf(
      fmaxf(fmaxf(fmaxf(d[0],d[1]),fmaxf(d[2],d[3])), fmaxf(fmaxf(d[4],d[5]),fmaxf(d[6],d[7]))),
      fmaxf(fmaxf(fmaxf(d[8],d[9]),fmaxf(d[10],d[11])), fmaxf(fmaxf(d[12],d[13]),fmaxf(d[14],d[15]))));
}
static __device__ __forceinline__ float vtsum(const f32x16& d) {
    return ((((d[0]+d[1])+(d[2]+d[3])) + ((d[4]+d[5])+(d[6]+d[7])))
          + (((d[8]+d[9])+(d[10]+d[11])) + ((d[12]+d[13])+(d[14]+d[15]))));
}
// B-frags use the SAME (h,e)->k map as the A-frags, so k-permutation cancels.
static __device__ __forceinline__ void make_frags(const f32x16& q, short8& lo, short8& hi) {
    unsigned int X  = pkbf(q[0],  q[1]),  Z  = pkbf(q[2],  q[3]);
    unsigned int Y  = pkbf(q[4],  q[5]),  W  = pkbf(q[6],  q[7]);
    unsigned int X2 = pkbf(q[8],  q[9]),  Z2 = pkbf(q[10], q[11]);
    unsigned int Y2 = pkbf(q[12], q[13]), W2 = pkbf(q[14], q[15]);
    swp32(X, Y); swp32(Z, W); swp32(X2, Y2); swp32(Z2, W2);
    union { unsigned int w[4]; short8 s; } u;
    u.w[0] = X;  u.w[1] = Z;  u.w[2] = Y;  u.w[3] = W;  lo = u.s;
    u.w[0] = X2; u.w[1] = Z2; u.w[2] = Y2; u.w[3] = W2; hi = u.s;
}

// bf16 dump slot (offset in ushort units; <<4 = 16 bf16 per lane per t)
#define DUMP_OFF(rg_, t_) ((((size_t)(rg_) * SEQLEN + (t_)) * 64 + lane) << 4)

#define MF_CONSTS_ALL                                                     \
    f32x16 muv, c0v, c1v, li2m;                                           \
    _Pragma("unroll")                                                     \
    for (int i = 0; i < 16; ++i) {                                        \
        int m = (i & 3) + ((i >> 2) << 3) + (h << 2);                     \
        float ls = log_sig[m];                                            \
        muv[i]  = means[m];                                               \
        c1v[i]  = -0.5f * expf(-2.0f * ls) * F_LOG2E;                     \
        c0v[i]  = (-ls + F_NEG_HALF_LOG2PI) * F_LOG2E;                    \
        li2m[i] = log_init[m] * F_LOG2E;                                  \
    }

#define MF_AFRAGS                                                         \
    const float* Ar = Amat + r * 32 + (h << 3);                           \
    float4 a0_ = *(const float4*)(Ar),      a1_ = *(const float4*)(Ar + 4);  \
    float4 a2_ = *(const float4*)(Ar + 16), a3_ = *(const float4*)(Ar + 20); \
    short8 alo, ahi;                                                      \
    {                                                                     \
        union { unsigned int ww[4]; short8 s; } ua;                       \
        ua.ww[0] = pkbf(a0_.x, a0_.y); ua.ww[1] = pkbf(a0_.z, a0_.w);     \
        ua.ww[2] = pkbf(a1_.x, a1_.y); ua.ww[3] = pkbf(a1_.z, a1_.w);     \
        alo = ua.s;                                                       \
        ua.ww[0] = pkbf(a2_.x, a2_.y); ua.ww[1] = pkbf(a2_.z, a2_.w);     \
        ua.ww[2] = pkbf(a3_.x, a3_.y); ua.ww[3] = pkbf(a3_.z, a3_.w);     \
        ahi = ua.s;                                                       \
    }

// stage obvs[row0+rr][tbase .. tbase+span) into xsw[t][rr]; tbase%4==0, span%4==0
#define MF_STAGE(xsw, tbase, span)                                        \
    {                                                                     \
        const float* xr_ = obvs + (size_t)(row0 + r) * SEQLEN + (tbase);  \
        for (int tt = 4 * h; tt + 4 <= (span); tt += 8) {                 \
            float4 v_ = *(const float4*)(xr_ + tt);                       \
            xsw[tt + 0][r] = v_.x; xsw[tt + 1][r] = v_.y;                 \
            xsw[tt + 2][r] = v_.z; xsw[tt + 3][r] = v_.w;                 \
        }                                                                 \
        __threadfence_block();                                            \
    }

// K1: forward recursion only; CHUNK=8, HALO=32, 4096 waves (4/SIMD, (128,4)).
// Stores phi_t = d*rs (pre-emission, *2^60) bf16 to lfB. r11-proven body.
__global__ __launch_bounds__(128, 4) void hmm_fwd8(
    const float* __restrict__ obvs, const float* __restrict__ log_init,
    const float* __restrict__ Amat, const float* __restrict__ means,
    const float* __restrict__ log_sig, unsigned short* __restrict__ lfB)
{
    __shared__ float xs[2][SPAN_MAX][32];
    const int tid = threadIdx.x;
    const int w = tid >> 6, lane = tid & 63, h = lane >> 5, r = lane & 31;
    const int wgid = blockIdx.x * 2 + w;           // [0,4096)
    const int chunk = wgid & (NCHUNKS - 1);
    const int rg = wgid >> 9;
    const int row0 = rg << 5;

    MF_CONSTS_ALL;
    MF_AFRAGS;
    const f32x16 zro = (f32x16)0.0f;
    float (*xsw)[32] = xs[w];

    const int t0 = chunk * CHUNK, t1 = t0 + CHUNK;
    const int ts = (t0 > HALO) ? (t0 - HALO) : 0;
    MF_STAGE(xsw, ts, t1 - ts);
    f32x16 qh;
    {
        float x0 = xsw[0][r];
#pragma unroll
        for (int i = 0; i < 16; ++i) {
            float dx = x0 - muv[i];
            float cur = fmaf(c1v[i] * dx, dx, c0v[i]) + (ts == 0 ? li2m[i] : 0.0f);
            qh[i] = EXP2F(cur);
        }
        if (chunk == 0) {
            // phi_0 = normalized pi (f_0 = phi_0 * ev_0)
            f32x16 u;
#pragma unroll
            for (int i = 0; i < 16; ++i) u[i] = EXP2F(li2m[i]);
            float s = RCPF(xhalf_max(vtmax(u))) * SCALE60;
            uintv8 pk;
#pragma unroll
            for (int k = 0; k < 8; ++k) pk[k] = pkbf(u[2*k] * s, u[2*k+1] * s);
            *(uintv8*)(lfB + DUMP_OFF(rg, 0)) = pk;
        }
    }
    for (int t = ts + 1; t < t1; ++t) {
        short8 blo, bhi; make_frags(qh, blo, bhi);
        f32x16 d = __builtin_amdgcn_mfma_f32_32x32x16_bf16(alo, blo, zro, 0, 0, 0);
        d = __builtin_amdgcn_mfma_f32_32x32x16_bf16(ahi, bhi, d, 0, 0, 0);
        float rs = RCPF(xhalf_max(vtmax(d)));      // r11-proven max tree
        float x = xsw[t - ts][r];
        f32x16 phi;
#pragma unroll
        for (int i = 0; i < 16; ++i) {
            float dx = x - muv[i];
            float e2 = fmaf(c1v[i] * dx, dx, c0v[i]);
            phi[i] = d[i] * rs;
            qh[i] = phi[i] * EXP2F(e2);
        }
        if (t >= t0) {
            uintv8 pk;
#pragma unroll
            for (int k = 0; k < 8; ++k)
                pk[k] = pkbf(phi[2*k] * SCALE60, phi[2*k+1] * SCALE60);
            *(uintv8*)(lfB + DUMP_OFF(rg, t)) = pk;
        }
    }
}

// K2: backward recursion + fused combine. At each output t (< t1), bh = b_t
// and ev_t are already live; load phi_t, p = phi*bh*ev, log-softmax, transpose
// via 1-t os tile, write out[row][t][0..31] (128B/row x 32 rows).
__global__ __launch_bounds__(128, 4) void hmm_bwdcomb(
    const float* __restrict__ obvs, const float* __restrict__ log_init,
    const float* __restrict__ Amat, const float* __restrict__ means,
    const float* __restrict__ log_sig, const unsigned short* __restrict__ lfB,
    float* __restrict__ out)
{
    __shared__ float xs[2][SPAN_MAX][32];
    __shared__ float os[2][32][32];
    const int tid = threadIdx.x;
    const int w = tid >> 6, lane = tid & 63, h = lane >> 5, r = lane & 31;
    const int wgid = blockIdx.x * 2 + w;           // [0,4096)
    const int chunk = wgid & (NCHUNKS - 1);
    const int rg = wgid >> 9;
    const int row0 = rg << 5;

    MF_CONSTS_ALL;
    MF_AFRAGS;
    const f32x16 zro = (f32x16)0.0f;
    float (*xsw)[32] = xs[w];
    const int xr4 = (r & 7) << 2;

    const int t0 = chunk * CHUNK, t1 = t0 + CHUNK;
    int tsb = t1 - 1 + HALO;
    if (tsb > SEQLEN - 1) tsb = SEQLEN - 1;
    MF_STAGE(xsw, t0, tsb - t0 + 1);

    f32x16 bh;
    if (tsb == SEQLEN - 1) {
        // exact init b(T-1) = exp2(li2m), max-normalized (chunks 508..511)
        float lm = xhalf_max(vtmax(li2m));
#pragma unroll
        for (int i = 0; i < 16; ++i) bh[i] = EXP2F(li2m[i] - lm);
    } else {
#pragma unroll
        for (int i = 0; i < 16; ++i) bh[i] = 1.0f;
    }

    for (int t = tsb; t >= t0; --t) {
        float x = xsw[t - t0][r];
        f32x16 ev;
#pragma unroll
        for (int i = 0; i < 16; ++i) {
            float dx = x - muv[i];
            ev[i] = EXP2F(fmaf(c1v[i] * dx, dx, c0v[i]));
        }
        if (t < t1) {
            // combine at t: p = phi_t * b_t * ev_t (scales cancel in z)
            uintv8 Fw = *(const uintv8*)(lfB + DUMP_OFF(rg, t));
            f32x16 p;
#pragma unroll
            for (int i = 0; i < 16; ++i) {
                unsigned int fw = Fw[i >> 1];
                float fv = __int_as_float((i & 1) ? (fw & 0xffff0000u) : (fw << 16));
                p[i] = fv * bh[i] * ev[i];
            }
            float z = LOG2F(xhalf_add(vtsum(p)));
            f32x16 g;
#pragma unroll
            for (int i = 0; i < 16; ++i) g[i] = (LOG2F(p[i]) - z) * F_LN2;
            float* orow = &os[w][r][0];
            int cb = h << 2;
            float4 v0 = {g[0],  g[1],  g[2],  g[3]};
            float4 v1 = {g[4],  g[5],  g[6],  g[7]};
            float4 v2 = {g[8],  g[9],  g[10], g[11]};
            float4 v3 = {g[12], g[13], g[14], g[15]};
            *(float4*)(orow + ((cb + 0)  ^ xr4)) = v0;
            *(float4*)(orow + ((cb + 8)  ^ xr4)) = v1;
            *(float4*)(orow + ((cb + 16) ^ xr4)) = v2;
            *(float4*)(orow + ((cb + 24) ^ xr4)) = v3;
            __threadfence_block();
            {
                int q_ = lane & 1, r2 = lane >> 1;
                const float* orf = &os[w][r2][0];
                float* gb = out + (size_t)(row0 + r2) * (SEQLEN * NSTATES)
                                + (size_t)t * NSTATES;
#pragma unroll
                for (int k_ = 0; k_ < 4; ++k_) {
                    int L = (k_ << 3) + (q_ << 2);
                    *(float4*)(gb + L) = *(const float4*)(orf + (L ^ ((r2 & 7) << 2)));
                }
            }
            __threadfence_block();
        }
        if (t > t0) {
            f32x16 wv;
#pragma unroll
            for (int i = 0; i < 16; ++i) wv[i] = bh[i] * ev[i];
            short8 blo, bhi; make_frags(wv, blo, bhi);
            f32x16 d = __builtin_amdgcn_mfma_f32_32x32x16_bf16(alo, blo, zro, 0, 0, 0);
            d = __builtin_amdgcn_mfma_f32_32x32x16_bf16(ahi, bhi, d, 0, 0, 0);
            float rs = RCPF(xhalf_max(vtmax(d)));  // r11-proven max tree
#pragma unroll
            for (int i = 0; i < 16; ++i) bh[i] = d[i] * rs;
        }
    }
}

extern "C" void kernel_launch(void* const* d_in, const int* in_sizes, int n_in,
                              void* d_out, int out_size, void* d_ws, size_t ws_size,
                              hipStream_t stream) {
    const float* obvs     = (const float*)d_in[0];
    const float* log_init = (const float*)d_in[1];
    const float* Amat     = (const float*)d_in[2];
    const float* means    = (const float*)d_in[3];
    const float* log_sig  = (const float*)d_in[4];
    float* out = (float*)d_out;

    unsigned short* lfB = (unsigned short*)d_ws;   // 67 MB (ws >= 192 MB, est. r6/7)

    hipLaunchKernelGGL(hmm_fwd8, dim3(2048), dim3(128), 0, stream,
                       obvs, log_init, Amat, means, log_sig, lfB);
    hipLaunchKernelGGL(hmm_bwdcomb, dim3(2048), dim3(128), 0, stream,
                       obvs, log_init, Amat, means, log_sig, lfB, out);
}